// Round 1
// baseline (6802.383 us; speedup 1.0000x reference)
//
#include <hip/hip_runtime.h>
#include <cstdint>

typedef __attribute__((ext_vector_type(8))) short bf16x8;
typedef __attribute__((ext_vector_type(4))) float f32x4;
typedef unsigned short u16;

// ---------- bf16 helpers (round-to-nearest-even) ----------
__device__ __forceinline__ u16 f2bf(float x) {
  unsigned u = __builtin_bit_cast(unsigned, x);
  return (u16)((u + 0x7FFFu + ((u >> 16) & 1u)) >> 16);
}
__device__ __forceinline__ float bf2f(u16 h) {
  unsigned u = ((unsigned)h) << 16;
  return __builtin_bit_cast(float, u);
}
__device__ __forceinline__ f32x4 mfma16(bf16x8 a, bf16x8 b, f32x4 c) {
  return __builtin_amdgcn_mfma_f32_16x16x32_bf16(a, b, c, 0, 0, 0);
}

// ---------- setup kernels ----------
__global__ void k_round(const float* __restrict__ whh, const float* __restrict__ wun,
                        u16* __restrict__ whhb, u16* __restrict__ wunb) {
  int i = blockIdx.x * 256 + threadIdx.x, st = 1024 * 256;
  for (int j = i; j < 3072 * 1024; j += st) whhb[j] = f2bf(whh[j]);
  for (int j = i; j < 256 * 1024; j += st) wunb[j] = f2bf(wun[j]);
}

__global__ void k_hinit(const float* __restrict__ c, float* __restrict__ h32,
                        u16* __restrict__ hhi, u16* __restrict__ hlo) {
  int i = blockIdx.x * 256 + threadIdx.x;  // 262144 threads
  float v = c[i];
  h32[i] = v;
  u16 hi = f2bf(v);
  hhi[i] = hi;
  hlo[i] = f2bf(v - bf2f(hi));
}

// W_comb = W_ih @ W_tok : [3072x1024]*[1024x256] -> bf16 [3072][256], fp32 accumulate
__global__ void k_wcomb(const float* __restrict__ wih, const float* __restrict__ wtok,
                        u16* __restrict__ wcb) {
  __shared__ float la[64][33];
  __shared__ float lb[32][65];
  int i0 = blockIdx.x << 6, j0 = blockIdx.y << 6;
  int tid = threadIdx.x;
  int ty = tid >> 4, tx = tid & 15;
  float acc[4][4] = {};
  for (int k0 = 0; k0 < 1024; k0 += 32) {
    __syncthreads();
#pragma unroll
    for (int i = 0; i < 8; ++i) {
      int r = (tid >> 5) + i * 8, cc = tid & 31;
      la[r][cc] = wih[(size_t)(i0 + r) * 1024 + k0 + cc];
    }
#pragma unroll
    for (int i = 0; i < 8; ++i) {
      int idx = i * 256 + tid;
      int r = idx >> 6, cc = idx & 63;
      lb[r][cc] = wtok[(size_t)(k0 + r) * 256 + j0 + cc];
    }
    __syncthreads();
#pragma unroll
    for (int kk = 0; kk < 32; ++kk) {
      float av[4], bv[4];
#pragma unroll
      for (int ii = 0; ii < 4; ++ii) av[ii] = la[ty * 4 + ii][kk];
#pragma unroll
      for (int jj = 0; jj < 4; ++jj) bv[jj] = lb[kk][tx * 4 + jj];
#pragma unroll
      for (int ii = 0; ii < 4; ++ii)
#pragma unroll
        for (int jj = 0; jj < 4; ++jj) acc[ii][jj] += av[ii] * bv[jj];
    }
  }
#pragma unroll
  for (int ii = 0; ii < 4; ++ii)
#pragma unroll
    for (int jj = 0; jj < 4; ++jj)
      wcb[(size_t)(i0 + ty * 4 + ii) * 256 + j0 + tx * 4 + jj] = f2bf(acc[ii][jj]);
}

// bc[j] = sum_e W_ih[j][e]*b_tok[e] + b_ih[j]
__global__ void k_bcomb(const float* __restrict__ wih, const float* __restrict__ btok,
                        const float* __restrict__ bih, float* __restrict__ bc) {
  __shared__ float red[256];
  int j = blockIdx.x, t = threadIdx.x;
  float s = 0.f;
  for (int e = t; e < 1024; e += 256) s += wih[(size_t)j * 1024 + e] * btok[e];
  red[t] = s;
  __syncthreads();
  for (int off = 128; off > 0; off >>= 1) {
    if (t < off) red[t] += red[t + off];
    __syncthreads();
  }
  if (t == 0) bc[j] = red[0] + bih[j];
}

// xs[k][b][d] = x[b][d][127+k] for k in [1,128), split to bf16 hi/lo.  LDS transpose.
__global__ void k_xprep(const float* __restrict__ x, u16* __restrict__ xhi,
                        u16* __restrict__ xlo) {
  __shared__ float t[64][129];
  int bid = blockIdx.x;
  int b = bid >> 2, d0 = (bid & 3) << 6;
  int tid = threadIdx.x;
#pragma unroll
  for (int i = 0; i < 32; ++i) {
    int idx = i * 256 + tid;
    int dd = idx >> 7, tt = idx & 127;
    t[dd][tt] = x[(size_t)b * 65536 + (size_t)(d0 + dd) * 256 + 128 + tt];
  }
  __syncthreads();
#pragma unroll
  for (int i = 0; i < 32; ++i) {
    int idx = i * 256 + tid;
    int dd = idx & 63, kk = idx >> 6;
    if (kk < 127) {
      float v = t[dd][kk];
      u16 hi = f2bf(v);
      int o = (kk + 1) * 65536 + b * 256 + d0 + dd;
      xhi[o] = hi;
      xlo[o] = f2bf(v - bf2f(hi));
    }
  }
}

// ---------- per-step GEMM: 4 preact planes (r, z, n_h, n_x), per-wave K-split partials ----------
// planes: p=0: h.Whh_r + x.Wc_r ; p=1: same for z ; p=2: h.Whh_n ; p=3: x.Wc_n
// pre layout: [wave 0..3][plane 0..3][256][1024] f32 partials
__launch_bounds__(256, 1)
__global__ void k_step(const u16* __restrict__ hhi, const u16* __restrict__ hlo,
                       const u16* __restrict__ xhi, const u16* __restrict__ xlo,
                       const u16* __restrict__ whh, const u16* __restrict__ wc,
                       float* __restrict__ pre, int use_x) {
  __shared__ u16 lds[4][3][64][32];  // per-wave: [A_hi, A_lo, B] tiles, 64 rows x 32 k (bf16)
  int bid = blockIdx.x;
  // XCD-aware decode: bid%8 selects an n-group so each XCD's L2 keeps its W slice
  int xcd = bid & 7, rest = bid >> 3;
  int mt = rest & 3, sn = rest >> 2;
  int ntile = xcd * 8 + sn;        // [0,64)
  int p = ntile >> 4;              // plane
  int n0 = (ntile & 15) << 6;
  int m0 = mt << 6;
  if (p == 3 && !use_x) return;
  int w = threadIdx.x >> 6, lane = threadIdx.x & 63;
  int nc = (p < 2) ? (use_x ? 10 : 8) : (p == 2 ? 8 : 2);
  int bh = (p == 2 ? 2048 : (p << 10)) + n0;  // W_hh row base
  int bx = (p == 3 ? 2048 : (p << 10)) + n0;  // W_comb row base
  f32x4 acc[4][4] = {};
  uint4 ra[12], rb[12];

  auto loadc = [&](int c2, uint4* R) {
    bool hx = (p == 3) ? false : (c2 < 8);
    int cc = hx ? c2 : (c2 - ((p == 3) ? 0 : 8));
    const u16 *A0, *A1, *Bp;
    int sA, sB, kb;
    if (hx) {
      A0 = hhi; A1 = hlo; sA = 1024; sB = 1024;
      kb = (w << 8) + (cc << 5);
      Bp = whh + (size_t)bh * 1024;
    } else {
      A0 = xhi; A1 = xlo; sA = 256; sB = 256;
      kb = (w << 6) + (cc << 5);
      Bp = wc + (size_t)bx * 256;
    }
    int rr = lane >> 2, uu = (lane & 3) * 8;
#pragma unroll
    for (int s = 0; s < 4; ++s) {
      int row = s * 16 + rr;
      R[s]     = *(const uint4*)(A0 + (size_t)(m0 + row) * sA + kb + uu);
      R[4 + s] = *(const uint4*)(A1 + (size_t)(m0 + row) * sA + kb + uu);
      R[8 + s] = *(const uint4*)(Bp + (size_t)row * sB + kb + uu);
    }
  };
  auto wlds = [&](uint4* R) {
    int rr = lane >> 2, u0 = lane & 3;
#pragma unroll
    for (int s = 0; s < 4; ++s) {
      int row = s * 16 + rr;
      int su = (u0 ^ (row & 3)) * 8;  // XOR swizzle on 16B units (bijective per row)
      *(uint4*)&lds[w][0][row][su] = R[s];
      *(uint4*)&lds[w][1][row][su] = R[4 + s];
      *(uint4*)&lds[w][2][row][su] = R[8 + s];
    }
  };
  auto comp = [&]() {
    int l15 = lane & 15, l4 = lane >> 4;
    int ru = (l4 ^ (l15 & 3)) * 8;  // same swizzle on read (row&3 == l15&3 since 16|rowbase)
    bf16x8 ah[4], al[4], bb[4];
#pragma unroll
    for (int mi = 0; mi < 4; ++mi) {
      ah[mi] = *(const bf16x8*)&lds[w][0][mi * 16 + l15][ru];
      al[mi] = *(const bf16x8*)&lds[w][1][mi * 16 + l15][ru];
    }
#pragma unroll
    for (int ni = 0; ni < 4; ++ni)
      bb[ni] = *(const bf16x8*)&lds[w][2][ni * 16 + l15][ru];
#pragma unroll
    for (int mi = 0; mi < 4; ++mi)
#pragma unroll
      for (int ni = 0; ni < 4; ++ni) acc[mi][ni] = mfma16(ah[mi], bb[ni], acc[mi][ni]);
#pragma unroll
    for (int mi = 0; mi < 4; ++mi)
#pragma unroll
      for (int ni = 0; ni < 4; ++ni) acc[mi][ni] = mfma16(al[mi], bb[ni], acc[mi][ni]);
  };

  loadc(0, ra);
  for (int c = 0; c < nc; c += 2) {  // nc always even
    wlds(ra);
    if (c + 1 < nc) loadc(c + 1, rb);
    comp();
    wlds(rb);
    if (c + 2 < nc) loadc(c + 2, ra);
    comp();
  }

  int l15 = lane & 15, l4 = lane >> 4;
  float* prew = pre + (((size_t)(w * 4 + p)) << 18);
#pragma unroll
  for (int mi = 0; mi < 4; ++mi)
#pragma unroll
    for (int ni = 0; ni < 4; ++ni) {
      int cc2 = n0 + ni * 16 + l15;
#pragma unroll
      for (int r = 0; r < 4; ++r) {
        int rr2 = m0 + mi * 16 + l4 * 4 + r;  // verified C layout: col=lane&15, row=(lane>>4)*4+reg
        prew[(size_t)rr2 * 1024 + cc2] = acc[mi][ni][r];
      }
    }
}

// ---------- per-step pointwise: gates + h update + hi/lo split + ys ----------
__global__ void k_point(const float* __restrict__ pre, const float* __restrict__ bgi,
                        const float* __restrict__ bhh, const float* __restrict__ hold,
                        float* __restrict__ hnew, u16* __restrict__ hhi, u16* __restrict__ hlo,
                        u16* __restrict__ ys, int kstep, int use_x) {
  int i = blockIdx.x * 256 + threadIdx.x;  // 65536 threads x 4 elems
  int m = i >> 8, e4 = (i & 255) << 2;
  const float4* P = (const float4*)pre;
  int base = (m << 8) + (e4 >> 2);
  float pr[4] = {}, pz[4] = {}, pnh[4] = {}, pnx[4] = {};
#pragma unroll
  for (int w = 0; w < 4; ++w) {
    float4 a = P[((w * 4 + 0) << 16) + base];
    float4 b = P[((w * 4 + 1) << 16) + base];
    float4 c = P[((w * 4 + 2) << 16) + base];
    pr[0] += a.x; pr[1] += a.y; pr[2] += a.z; pr[3] += a.w;
    pz[0] += b.x; pz[1] += b.y; pz[2] += b.z; pz[3] += b.w;
    pnh[0] += c.x; pnh[1] += c.y; pnh[2] += c.z; pnh[3] += c.w;
    if (use_x) {
      float4 d = P[((w * 4 + 3) << 16) + base];
      pnx[0] += d.x; pnx[1] += d.y; pnx[2] += d.z; pnx[3] += d.w;
    }
  }
  float4 ho = *(const float4*)&hold[(m << 10) + e4];
  float hov[4] = {ho.x, ho.y, ho.z, ho.w};
#pragma unroll
  for (int j = 0; j < 4; ++j) {
    int e = e4 + j;
    float gr = pr[j] + bgi[e] + bhh[e];
    float gz = pz[j] + bgi[1024 + e] + bhh[1024 + e];
    float gh = pnh[j] + bhh[2048 + e];
    float gx = (use_x ? pnx[j] : 0.f) + bgi[2048 + e];
    float r = 1.f / (1.f + __expf(-gr));
    float z = 1.f / (1.f + __expf(-gz));
    float n = 1.f - 2.f / (1.f + __expf(2.f * (gx + r * gh)));
    float h = (1.f - z) * n + z * hov[j];
    int idx = (m << 10) + e;
    hnew[idx] = h;
    u16 hi = f2bf(h);
    hhi[idx] = hi;
    hlo[idx] = f2bf(h - bf2f(hi));
    ys[(((m << 7) + kstep) << 10) + e] = hi;  // ys[b][k][e]
  }
}

// ---------- untokenizer: out[b][d][k] = sum_e Wun[d][e]*ys[b][k][e] + bun[d] ----------
__launch_bounds__(256, 1)
__global__ void k_untok(const u16* __restrict__ wun, const u16* __restrict__ ys,
                        const float* __restrict__ bun, float* __restrict__ out) {
  __shared__ u16 lds[4][2][64][32];
  int bid = blockIdx.x;
  int b = bid >> 1, dt = bid & 1;
  int w = threadIdx.x >> 6, lane = threadIdx.x & 63;
  int dbase = dt * 128 + (w >> 1) * 64;
  int kbase = (w & 1) * 64;
  const u16* ysb = ys + ((size_t)(b * 128 + kbase)) * 1024;
  const u16* wb = wun + (size_t)dbase * 1024;
  f32x4 acc[4][4] = {};
  uint4 ra[8], rb[8];

  auto loadc = [&](int c2, uint4* R) {
    int kb = c2 << 5;
    int rr = lane >> 2, uu = (lane & 3) * 8;
#pragma unroll
    for (int s = 0; s < 4; ++s) {
      int row = s * 16 + rr;
      R[s]     = *(const uint4*)(wb + (size_t)row * 1024 + kb + uu);
      R[4 + s] = *(const uint4*)(ysb + (size_t)row * 1024 + kb + uu);
    }
  };
  auto wlds = [&](uint4* R) {
    int rr = lane >> 2, u0 = lane & 3;
#pragma unroll
    for (int s = 0; s < 4; ++s) {
      int row = s * 16 + rr;
      int su = (u0 ^ (row & 3)) * 8;
      *(uint4*)&lds[w][0][row][su] = R[s];
      *(uint4*)&lds[w][1][row][su] = R[4 + s];
    }
  };
  auto comp = [&]() {
    int l15 = lane & 15, l4 = lane >> 4;
    int ru = (l4 ^ (l15 & 3)) * 8;
    bf16x8 aa[4], bb[4];
#pragma unroll
    for (int mi = 0; mi < 4; ++mi) aa[mi] = *(const bf16x8*)&lds[w][0][mi * 16 + l15][ru];
#pragma unroll
    for (int ni = 0; ni < 4; ++ni) bb[ni] = *(const bf16x8*)&lds[w][1][ni * 16 + l15][ru];
#pragma unroll
    for (int mi = 0; mi < 4; ++mi)
#pragma unroll
      for (int ni = 0; ni < 4; ++ni) acc[mi][ni] = mfma16(aa[mi], bb[ni], acc[mi][ni]);
  };

  loadc(0, ra);
  for (int c = 0; c < 32; c += 2) {
    wlds(ra);
    if (c + 1 < 32) loadc(c + 1, rb);
    comp();
    wlds(rb);
    if (c + 2 < 32) loadc(c + 2, ra);
    comp();
  }
  int l15 = lane & 15, l4 = lane >> 4;
#pragma unroll
  for (int mi = 0; mi < 4; ++mi)
#pragma unroll
    for (int ni = 0; ni < 4; ++ni)
#pragma unroll
      for (int r = 0; r < 4; ++r) {
        int dd = dbase + mi * 16 + l4 * 4 + r;
        int kk = kbase + ni * 16 + l15;
        out[(size_t)b * 32768 + (size_t)dd * 128 + kk] = acc[mi][ni][r] + bun[dd];
      }
}

// ---------- launch ----------
extern "C" void kernel_launch(void* const* d_in, const int* in_sizes, int n_in,
                              void* d_out, int out_size, void* d_ws, size_t ws_size,
                              hipStream_t stream) {
  const float* c_in = (const float*)d_in[0];
  const float* x_in = (const float*)d_in[2];
  const float* Wih  = (const float*)d_in[3];
  const float* Whh  = (const float*)d_in[4];
  const float* bih  = (const float*)d_in[5];
  const float* bhh  = (const float*)d_in[6];
  const float* Wtok = (const float*)d_in[7];
  const float* btok = (const float*)d_in[8];
  const float* Wun  = (const float*)d_in[9];
  const float* bun  = (const float*)d_in[10];
  float* out = (float*)d_out;
  char* ws = (char*)d_ws;

  const size_t OW_HH = 0;                         // u16 [3072][1024]
  const size_t OW_C  = 6291456;                   // u16 [3072][256]
  const size_t OW_UN = 7864320;                   // u16 [256][1024]
  const size_t OBC   = 8388608;                   // f32 [3072]
  const size_t OXHI  = 8400896;                   // u16 [128][256][256]
  const size_t OXLO  = 25178112;
  const size_t OH32  = 41955328;                  // f32 [2][256][1024]
  const size_t OHHI  = 44052480;                  // u16 [2][256][1024]
  const size_t OHLO  = 46149632 - 1048576;        // = 45101056
  const size_t OPRE  = 46149632;                  // f32 [16][256][1024]
  const size_t OYS   = 62926848;                  // u16 [256][128][1024]
  const size_t NEED  = 130035712;
  if (ws_size < NEED) return;

  u16* whh_b = (u16*)(ws + OW_HH);
  u16* wc_b  = (u16*)(ws + OW_C);
  u16* wun_b = (u16*)(ws + OW_UN);
  float* bc  = (float*)(ws + OBC);
  u16* xhi   = (u16*)(ws + OXHI);
  u16* xlo   = (u16*)(ws + OXLO);
  float* h32 = (float*)(ws + OH32);
  u16* hhi   = (u16*)(ws + OHHI);
  u16* hlo   = (u16*)(ws + OHLO);
  float* pre = (float*)(ws + OPRE);
  u16* ys    = (u16*)(ws + OYS);

  k_round<<<1024, 256, 0, stream>>>(Whh, Wun, whh_b, wun_b);
  k_wcomb<<<dim3(48, 4), 256, 0, stream>>>(Wih, Wtok, wc_b);
  k_bcomb<<<3072, 256, 0, stream>>>(Wih, btok, bih, bc);
  k_xprep<<<1024, 256, 0, stream>>>(x_in, xhi, xlo);
  k_hinit<<<1024, 256, 0, stream>>>(c_in, h32, hhi, hlo);

  for (int k = 0; k < 128; ++k) {
    int cur = k & 1, nxt = cur ^ 1;
    int use_x = (k > 0) ? 1 : 0;
    k_step<<<256, 256, 0, stream>>>(hhi + (size_t)cur * 262144, hlo + (size_t)cur * 262144,
                                    xhi + (size_t)k * 65536, xlo + (size_t)k * 65536,
                                    whh_b, wc_b, pre, use_x);
    k_point<<<256, 256, 0, stream>>>(pre, (k == 0) ? bih : bc, bhh,
                                     h32 + (size_t)cur * 262144, h32 + (size_t)nxt * 262144,
                                     hhi + (size_t)nxt * 262144, hlo + (size_t)nxt * 262144,
                                     ys, k, use_x);
  }
  k_untok<<<512, 256, 0, stream>>>(wun_b, ys, bun, out);
}

// Round 2
// 3634.550 us; speedup vs baseline: 1.8716x; 1.8716x over previous
//
#include <hip/hip_runtime.h>
#include <cstdint>

typedef __attribute__((ext_vector_type(8))) short bf16x8;
typedef __attribute__((ext_vector_type(4))) float f32x4;
typedef unsigned short u16;

// ---------- bf16 helpers (round-to-nearest-even) ----------
__device__ __forceinline__ u16 f2bf(float x) {
  unsigned u = __builtin_bit_cast(unsigned, x);
  return (u16)((u + 0x7FFFu + ((u >> 16) & 1u)) >> 16);
}
__device__ __forceinline__ float bf2f(u16 h) {
  unsigned u = ((unsigned)h) << 16;
  return __builtin_bit_cast(float, u);
}
__device__ __forceinline__ f32x4 mfma16(bf16x8 a, bf16x8 b, f32x4 c) {
  return __builtin_amdgcn_mfma_f32_16x16x32_bf16(a, b, c, 0, 0, 0);
}
__device__ __forceinline__ bf16x8 bc8(uint4 v) { return __builtin_bit_cast(bf16x8, v); }

// ---------- setup kernels (validated round 0) ----------
__global__ void k_round(const float* __restrict__ whh, const float* __restrict__ wun,
                        u16* __restrict__ whhb, u16* __restrict__ wunb) {
  int i = blockIdx.x * 256 + threadIdx.x, st = 1024 * 256;
  for (int j = i; j < 3072 * 1024; j += st) whhb[j] = f2bf(whh[j]);
  for (int j = i; j < 256 * 1024; j += st) wunb[j] = f2bf(wun[j]);
}

__global__ void k_hinit(const float* __restrict__ c, u16* __restrict__ hhi,
                        u16* __restrict__ hlo) {
  int i = blockIdx.x * 256 + threadIdx.x;  // 262144 threads
  float v = c[i];
  u16 hi = f2bf(v);
  hhi[i] = hi;
  hlo[i] = f2bf(v - bf2f(hi));
}

// W_comb = W_ih @ W_tok : fp32 accumulate -> bf16 [3072][256]
__global__ void k_wcomb(const float* __restrict__ wih, const float* __restrict__ wtok,
                        u16* __restrict__ wcb) {
  __shared__ float la[64][33];
  __shared__ float lb[32][65];
  int i0 = blockIdx.x << 6, j0 = blockIdx.y << 6;
  int tid = threadIdx.x;
  int ty = tid >> 4, tx = tid & 15;
  float acc[4][4] = {};
  for (int k0 = 0; k0 < 1024; k0 += 32) {
    __syncthreads();
#pragma unroll
    for (int i = 0; i < 8; ++i) {
      int r = (tid >> 5) + i * 8, cc = tid & 31;
      la[r][cc] = wih[(size_t)(i0 + r) * 1024 + k0 + cc];
    }
#pragma unroll
    for (int i = 0; i < 8; ++i) {
      int idx = i * 256 + tid;
      int r = idx >> 6, cc = idx & 63;
      lb[r][cc] = wtok[(size_t)(k0 + r) * 256 + j0 + cc];
    }
    __syncthreads();
#pragma unroll
    for (int kk = 0; kk < 32; ++kk) {
      float av[4], bv[4];
#pragma unroll
      for (int ii = 0; ii < 4; ++ii) av[ii] = la[ty * 4 + ii][kk];
#pragma unroll
      for (int jj = 0; jj < 4; ++jj) bv[jj] = lb[kk][tx * 4 + jj];
#pragma unroll
      for (int ii = 0; ii < 4; ++ii)
#pragma unroll
        for (int jj = 0; jj < 4; ++jj) acc[ii][jj] += av[ii] * bv[jj];
    }
  }
#pragma unroll
  for (int ii = 0; ii < 4; ++ii)
#pragma unroll
    for (int jj = 0; jj < 4; ++jj)
      wcb[(size_t)(i0 + ty * 4 + ii) * 256 + j0 + tx * 4 + jj] = f2bf(acc[ii][jj]);
}

__global__ void k_bcomb(const float* __restrict__ wih, const float* __restrict__ btok,
                        const float* __restrict__ bih, float* __restrict__ bc) {
  __shared__ float red[256];
  int j = blockIdx.x, t = threadIdx.x;
  float s = 0.f;
  for (int e = t; e < 1024; e += 256) s += wih[(size_t)j * 1024 + e] * btok[e];
  red[t] = s;
  __syncthreads();
  for (int off = 128; off > 0; off >>= 1) {
    if (t < off) red[t] += red[t + off];
    __syncthreads();
  }
  if (t == 0) bc[j] = red[0] + bih[j];
}

// xs[k][b][d] = x[b][d][127+k] for k in [1,128), split to bf16 hi/lo.
__global__ void k_xprep(const float* __restrict__ x, u16* __restrict__ xhi,
                        u16* __restrict__ xlo) {
  __shared__ float t[64][129];
  int bid = blockIdx.x;
  int b = bid >> 2, d0 = (bid & 3) << 6;
  int tid = threadIdx.x;
#pragma unroll
  for (int i = 0; i < 32; ++i) {
    int idx = i * 256 + tid;
    int dd = idx >> 7, tt = idx & 127;
    t[dd][tt] = x[(size_t)b * 65536 + (size_t)(d0 + dd) * 256 + 128 + tt];
  }
  __syncthreads();
#pragma unroll
  for (int i = 0; i < 32; ++i) {
    int idx = i * 256 + tid;
    int dd = idx & 63, kk = idx >> 6;
    if (kk < 127) {
      float v = t[dd][kk];
      u16 hi = f2bf(v);
      int o = (kk + 1) * 65536 + b * 256 + d0 + dd;
      xhi[o] = hi;
      xlo[o] = f2bf(v - bf2f(hi));
    }
  }
}

// ---------- fused step: GEMM (4 planes) + gates + h update, no LDS, no partials ----------
// WG tile: [64 m x 16 e] x all planes; wave w owns m-rows [w*16, w*16+16).
__launch_bounds__(256, 1)
__global__ void k_step2(const u16* __restrict__ hhi, const u16* __restrict__ hlo,
                        const u16* __restrict__ xhi, const u16* __restrict__ xlo,
                        const u16* __restrict__ whh, const u16* __restrict__ wc,
                        const float* __restrict__ bgi, const float* __restrict__ bhh,
                        u16* __restrict__ nhhi, u16* __restrict__ nhlo,
                        u16* __restrict__ ysp, int use_x) {
  int bid = blockIdx.x;
  int xcd = bid & 7, t = bid >> 3;
  int m0 = (t & 3) << 6;
  int e0 = (((t >> 2) << 3) + xcd) << 4;  // e-tile XCD-pinned: et&7 == bid&7
  int w = threadIdx.x >> 6, lane = threadIdx.x & 63;
  int l15 = lane & 15, l4 = lane >> 4;
  int arow = m0 + w * 16 + l15;
  const u16* Ah = hhi + (size_t)arow * 1024 + l4 * 8;
  const u16* Al = hlo + (size_t)arow * 1024 + l4 * 8;
  const u16* B0 = whh + (size_t)(e0 + l15) * 1024 + l4 * 8;
  const u16* B1 = whh + (size_t)(1024 + e0 + l15) * 1024 + l4 * 8;
  const u16* B2 = whh + (size_t)(2048 + e0 + l15) * 1024 + l4 * 8;
  const u16* Xh = xhi + (size_t)arow * 256 + l4 * 8;
  const u16* Xl = xlo + (size_t)arow * 256 + l4 * 8;
  const u16* C0 = wc + (size_t)(e0 + l15) * 256 + l4 * 8;
  const u16* C1 = wc + (size_t)(1024 + e0 + l15) * 256 + l4 * 8;
  const u16* C2 = wc + (size_t)(2048 + e0 + l15) * 256 + l4 * 8;

  int e = e0 + l15;
  float br = bgi[e] + bhh[e];
  float bz = bgi[1024 + e] + bhh[1024 + e];
  float bnh = bhh[2048 + e];
  float bnx = bgi[2048 + e];
  float hold[4];
#pragma unroll
  for (int j = 0; j < 4; ++j) {
    int r = m0 + w * 16 + l4 * 4 + j;
    hold[j] = bf2f(hhi[(size_t)r * 1024 + e]) + bf2f(hlo[(size_t)r * 1024 + e]);
  }

  // 8 independent accumulator chains (even/odd slots)
  f32x4 aR0{}, aR1{}, aZ0{}, aZ1{}, aN0{}, aN1{}, aX0{}, aX1{};

#define LD16(P, k) (*(const uint4*)((P) + (k)))

  // h-part: 16 slots of 64 K
#pragma unroll
  for (int s = 0; s < 16; ++s) {
    int k0 = s * 64;
    uint4 A0 = LD16(Ah, k0), A1 = LD16(Ah, k0 + 32);
    uint4 L0 = LD16(Al, k0), L1 = LD16(Al, k0 + 32);
    uint4 R0 = LD16(B0, k0), R1 = LD16(B0, k0 + 32);
    uint4 Z0 = LD16(B1, k0), Z1 = LD16(B1, k0 + 32);
    uint4 N0 = LD16(B2, k0), N1 = LD16(B2, k0 + 32);
    f32x4& aR = (s & 1) ? aR1 : aR0;
    f32x4& aZ = (s & 1) ? aZ1 : aZ0;
    f32x4& aN = (s & 1) ? aN1 : aN0;
    bf16x8 a0 = bc8(A0), a1 = bc8(A1), l0 = bc8(L0), l1 = bc8(L1);
    aR = mfma16(a0, bc8(R0), aR); aR = mfma16(l0, bc8(R0), aR);
    aR = mfma16(a1, bc8(R1), aR); aR = mfma16(l1, bc8(R1), aR);
    aZ = mfma16(a0, bc8(Z0), aZ); aZ = mfma16(l0, bc8(Z0), aZ);
    aZ = mfma16(a1, bc8(Z1), aZ); aZ = mfma16(l1, bc8(Z1), aZ);
    aN = mfma16(a0, bc8(N0), aN); aN = mfma16(l0, bc8(N0), aN);
    aN = mfma16(a1, bc8(N1), aN); aN = mfma16(l1, bc8(N1), aN);
  }

  // x-part: 4 slots of 64 K (skipped at k=0)
  if (use_x) {
#pragma unroll
    for (int s = 0; s < 4; ++s) {
      int k0 = s * 64;
      uint4 A0 = LD16(Xh, k0), A1 = LD16(Xh, k0 + 32);
      uint4 L0 = LD16(Xl, k0), L1 = LD16(Xl, k0 + 32);
      uint4 R0 = LD16(C0, k0), R1 = LD16(C0, k0 + 32);
      uint4 Z0 = LD16(C1, k0), Z1 = LD16(C1, k0 + 32);
      uint4 N0 = LD16(C2, k0), N1 = LD16(C2, k0 + 32);
      f32x4& aR = (s & 1) ? aR1 : aR0;
      f32x4& aZ = (s & 1) ? aZ1 : aZ0;
      f32x4& aX = (s & 1) ? aX1 : aX0;
      bf16x8 a0 = bc8(A0), a1 = bc8(A1), l0 = bc8(L0), l1 = bc8(L1);
      aR = mfma16(a0, bc8(R0), aR); aR = mfma16(l0, bc8(R0), aR);
      aR = mfma16(a1, bc8(R1), aR); aR = mfma16(l1, bc8(R1), aR);
      aZ = mfma16(a0, bc8(Z0), aZ); aZ = mfma16(l0, bc8(Z0), aZ);
      aZ = mfma16(a1, bc8(Z1), aZ); aZ = mfma16(l1, bc8(Z1), aZ);
      aX = mfma16(a0, bc8(N0), aX); aX = mfma16(l0, bc8(N0), aX);
      aX = mfma16(a1, bc8(N1), aX); aX = mfma16(l1, bc8(N1), aX);
    }
  }

  // fused pointwise (verified layout: col = lane&15, row = (lane>>4)*4 + reg)
#pragma unroll
  for (int j = 0; j < 4; ++j) {
    float gr = aR0[j] + aR1[j] + br;
    float gz = aZ0[j] + aZ1[j] + bz;
    float gh = aN0[j] + aN1[j] + bnh;
    float gx = aX0[j] + aX1[j] + bnx;
    float r = 1.f / (1.f + __expf(-gr));
    float z = 1.f / (1.f + __expf(-gz));
    float n = 1.f - 2.f / (1.f + __expf(2.f * (gx + r * gh)));
    float h = (1.f - z) * n + z * hold[j];
    int row = m0 + w * 16 + l4 * 4 + j;
    u16 hi = f2bf(h);
    size_t idx = (size_t)row * 1024 + e;
    nhhi[idx] = hi;
    nhlo[idx] = f2bf(h - bf2f(hi));
    ysp[(size_t)row * 131072 + e] = hi;  // ys[b][k][e], ysp pre-offset by k*1024
  }
}

// ---------- untokenizer (validated round 0) ----------
__launch_bounds__(256, 1)
__global__ void k_untok(const u16* __restrict__ wun, const u16* __restrict__ ys,
                        const float* __restrict__ bun, float* __restrict__ out) {
  __shared__ u16 lds[4][2][64][32];
  int bid = blockIdx.x;
  int b = bid >> 1, dt = bid & 1;
  int w = threadIdx.x >> 6, lane = threadIdx.x & 63;
  int dbase = dt * 128 + (w >> 1) * 64;
  int kbase = (w & 1) * 64;
  const u16* ysb = ys + ((size_t)(b * 128 + kbase)) * 1024;
  const u16* wb = wun + (size_t)dbase * 1024;
  f32x4 acc[4][4] = {};
  uint4 ra[8], rb[8];

  auto loadc = [&](int c2, uint4* R) {
    int kb = c2 << 5;
    int rr = lane >> 2, uu = (lane & 3) * 8;
#pragma unroll
    for (int s = 0; s < 4; ++s) {
      int row = s * 16 + rr;
      R[s]     = *(const uint4*)(wb + (size_t)row * 1024 + kb + uu);
      R[4 + s] = *(const uint4*)(ysb + (size_t)row * 1024 + kb + uu);
    }
  };
  auto wlds = [&](uint4* R) {
    int rr = lane >> 2, u0 = lane & 3;
#pragma unroll
    for (int s = 0; s < 4; ++s) {
      int row = s * 16 + rr;
      int su = (u0 ^ (row & 3)) * 8;
      *(uint4*)&lds[w][0][row][su] = R[s];
      *(uint4*)&lds[w][1][row][su] = R[4 + s];
    }
  };
  auto comp = [&]() {
    int l15 = lane & 15, l4 = lane >> 4;
    int ru = (l4 ^ (l15 & 3)) * 8;
    bf16x8 aa[4], bb[4];
#pragma unroll
    for (int mi = 0; mi < 4; ++mi) aa[mi] = *(const bf16x8*)&lds[w][0][mi * 16 + l15][ru];
#pragma unroll
    for (int ni = 0; ni < 4; ++ni) bb[ni] = *(const bf16x8*)&lds[w][1][ni * 16 + l15][ru];
#pragma unroll
    for (int mi = 0; mi < 4; ++mi)
#pragma unroll
      for (int ni = 0; ni < 4; ++ni) acc[mi][ni] = mfma16(aa[mi], bb[ni], acc[mi][ni]);
  };

  loadc(0, ra);
  for (int c = 0; c < 32; c += 2) {
    wlds(ra);
    if (c + 1 < 32) loadc(c + 1, rb);
    comp();
    wlds(rb);
    if (c + 2 < 32) loadc(c + 2, ra);
    comp();
  }
  int l15 = lane & 15, l4 = lane >> 4;
#pragma unroll
  for (int mi = 0; mi < 4; ++mi)
#pragma unroll
    for (int ni = 0; ni < 4; ++ni)
#pragma unroll
      for (int r = 0; r < 4; ++r) {
        int dd = dbase + mi * 16 + l4 * 4 + r;
        int kk = kbase + ni * 16 + l15;
        out[(size_t)b * 32768 + (size_t)dd * 128 + kk] = acc[mi][ni][r] + bun[dd];
      }
}

// ---------- launch ----------
extern "C" void kernel_launch(void* const* d_in, const int* in_sizes, int n_in,
                              void* d_out, int out_size, void* d_ws, size_t ws_size,
                              hipStream_t stream) {
  const float* c_in = (const float*)d_in[0];
  const float* x_in = (const float*)d_in[2];
  const float* Wih  = (const float*)d_in[3];
  const float* Whh  = (const float*)d_in[4];
  const float* bih  = (const float*)d_in[5];
  const float* bhh  = (const float*)d_in[6];
  const float* Wtok = (const float*)d_in[7];
  const float* btok = (const float*)d_in[8];
  const float* Wun  = (const float*)d_in[9];
  const float* bun  = (const float*)d_in[10];
  float* out = (float*)d_out;
  char* ws = (char*)d_ws;

  const size_t OW_HH = 0;                     // u16 [3072][1024]
  const size_t OW_C  = 6291456;               // u16 [3072][256]
  const size_t OW_UN = 7864320;               // u16 [256][1024]
  const size_t OBC   = 8388608;               // f32 [3072]
  const size_t OXHI  = 8400896;               // u16 [128][256][256]
  const size_t OXLO  = 25178112;              // u16 [128][256][256]
  const size_t OHHI  = 41955328;              // u16 [2][256][1024]
  const size_t OHLO  = 43003904;              // u16 [2][256][1024]
  const size_t OYS   = 44052480;              // u16 [256][128][1024]
  const size_t NEED  = 111161344;
  if (ws_size < NEED) return;

  u16* whh_b = (u16*)(ws + OW_HH);
  u16* wc_b  = (u16*)(ws + OW_C);
  u16* wun_b = (u16*)(ws + OW_UN);
  float* bc  = (float*)(ws + OBC);
  u16* xhi   = (u16*)(ws + OXHI);
  u16* xlo   = (u16*)(ws + OXLO);
  u16* hhi   = (u16*)(ws + OHHI);
  u16* hlo   = (u16*)(ws + OHLO);
  u16* ys    = (u16*)(ws + OYS);

  k_round<<<1024, 256, 0, stream>>>(Whh, Wun, whh_b, wun_b);
  k_wcomb<<<dim3(48, 4), 256, 0, stream>>>(Wih, Wtok, wc_b);
  k_bcomb<<<3072, 256, 0, stream>>>(Wih, btok, bih, bc);
  k_xprep<<<1024, 256, 0, stream>>>(x_in, xhi, xlo);
  k_hinit<<<1024, 256, 0, stream>>>(c_in, hhi, hlo);

  for (int k = 0; k < 128; ++k) {
    int cur = k & 1, nxt = cur ^ 1;
    k_step2<<<256, 256, 0, stream>>>(
        hhi + (size_t)cur * 262144, hlo + (size_t)cur * 262144,
        xhi + (size_t)k * 65536, xlo + (size_t)k * 65536,
        whh_b, wc_b, (k == 0) ? bih : bc, bhh,
        hhi + (size_t)nxt * 262144, hlo + (size_t)nxt * 262144,
        ys + (size_t)k * 1024, k > 0 ? 1 : 0);
  }
  k_untok<<<512, 256, 0, stream>>>(wun_b, ys, bun, out);
}